// Round 1
// baseline (1836.312 us; speedup 1.0000x reference)
//
#include <hip/hip_runtime.h>
#include <stdint.h>

// ---------------- problem constants ----------------
constexpr int CB = 8, CC = 4, CN = 2048, CE = 512, CF = 2048;
constexpr long long TOT = (long long)CB * CC * CN * CE;   // 67,108,864 elems
constexpr int G = 4;          // attention batches per group
constexpr int MCH = 8192;     // FFN row chunk
constexpr float SCALE = 0.04419417382415922f;  // 1/sqrt(512)
constexpr float MASK_SCALE = 5.0f;
constexpr float EPS = 1e-5f;

typedef unsigned short bf16_t;
typedef __attribute__((ext_vector_type(4))) float f32x4;
typedef __attribute__((ext_vector_type(8))) short s16x8;

#define DEV static __device__ __forceinline__

DEV unsigned short f2bf(float f) {
    unsigned u = __float_as_uint(f);
    unsigned r = (u + 0x7fffu + ((u >> 16) & 1u)) >> 16;
    return (unsigned short)r;
}
DEV float bf2f(unsigned short b) {
    return __uint_as_float(((unsigned)b) << 16);
}

typedef const __attribute__((address_space(1))) unsigned int* gptr_t;
typedef __attribute__((address_space(3))) unsigned int* lptr_t;
DEV void async16(const void* g, void* l) {
    __builtin_amdgcn_global_load_lds((gptr_t)g, (lptr_t)l, 16, 0, 0);
}

// ---------------- reductions (256-thread blocks = 4 waves) ----------------
DEV float blockSum256(float v, float* sm) {
    #pragma unroll
    for (int o = 32; o; o >>= 1) v += __shfl_xor(v, o);
    int w = threadIdx.x >> 6;
    __syncthreads();
    if ((threadIdx.x & 63) == 0) sm[w] = v;
    __syncthreads();
    return sm[0] + sm[1] + sm[2] + sm[3];
}
DEV float blockMax256(float v, float* sm) {
    #pragma unroll
    for (int o = 32; o; o >>= 1) v = fmaxf(v, __shfl_xor(v, o));
    int w = threadIdx.x >> 6;
    __syncthreads();
    if ((threadIdx.x & 63) == 0) sm[w] = v;
    __syncthreads();
    return fmaxf(fmaxf(sm[0], sm[1]), fmaxf(sm[2], sm[3]));
}

// ---------------- fp32 -> bf16 convert ----------------
__global__ __launch_bounds__(256) void cvt_f32_bf16_vec(
    const float* __restrict__ in, bf16_t* __restrict__ out, long long n) {
    long long i = ((long long)blockIdx.x * 256 + threadIdx.x) * 4;
    long long stride = (long long)gridDim.x * 1024;
    for (; i < n; i += stride) {
        float4 v = *reinterpret_cast<const float4*>(in + i);
        ushort4 u;
        u.x = f2bf(v.x); u.y = f2bf(v.y); u.z = f2bf(v.z); u.w = f2bf(v.w);
        *reinterpret_cast<ushort4*>(out + i) = u;
    }
}

// ---------------- transpose fp32[R][C] -> bf16[C][R], batched via z ----------------
__global__ __launch_bounds__(256) void transpose_f32_bf16(
    const float* __restrict__ in, bf16_t* __restrict__ out,
    int R, int Cc, long long sIn, long long sOut) {
    __shared__ float tile[32][33];
    const float* inz = in + (size_t)blockIdx.z * sIn;
    bf16_t* outz = out + (size_t)blockIdx.z * sOut;
    int rb = blockIdx.y * 32, cb = blockIdx.x * 32;
    int tx = threadIdx.x & 31, ty = threadIdx.x >> 5;  // ty 0..7
    #pragma unroll
    for (int i = 0; i < 32; i += 8)
        tile[ty + i][tx] = inz[(size_t)(rb + ty + i) * Cc + cb + tx];
    __syncthreads();
    #pragma unroll
    for (int i = 0; i < 32; i += 8)
        outz[(size_t)(cb + ty + i) * R + rb + tx] = f2bf(tile[tx][ty + i]);
}

// ---------------- GEMM: C[M,Nc] = A[M,K] @ B[Nc,K]^T  (bf16 in, fp32 acc) ----
// EPI 0: store fp32. EPI 1: +bias, ReLU, store bf16. EPI 2: +bias, store fp32.
// 128x128 tile, BK=32, 4 waves (2x2), m97 structure (global_load_lds width 16).
template <int EPI>
__global__ __launch_bounds__(256) void gemm_bt(
    const bf16_t* __restrict__ A, const bf16_t* __restrict__ B,
    void* __restrict__ Cptr, const float* __restrict__ bias,
    int M, int Nc, int K, long long sA, long long sB, long long sC) {
    __shared__ bf16_t As[128 * 32];
    __shared__ bf16_t Bs[128 * 32];
    const bf16_t* Az = A + (size_t)blockIdx.z * sA;
    const bf16_t* Bz = B + (size_t)blockIdx.z * sB;
    int tid = threadIdx.x;
    int lane = tid & 63, wid = tid >> 6;
    int wr = wid >> 1, wc = wid & 1;
    int brow = blockIdx.y * 128, bcol = blockIdx.x * 128;

    f32x4 acc[4][4] = {};

    int c0 = tid, c1 = tid + 256;
    const bf16_t* Ag0 = Az + (size_t)(brow + (c0 >> 2)) * K + (c0 & 3) * 8;
    const bf16_t* Ag1 = Az + (size_t)(brow + (c1 >> 2)) * K + (c1 & 3) * 8;
    const bf16_t* Bg0 = Bz + (size_t)(bcol + (c0 >> 2)) * K + (c0 & 3) * 8;
    const bf16_t* Bg1 = Bz + (size_t)(bcol + (c1 >> 2)) * K + (c1 & 3) * 8;

    for (int k0 = 0; k0 < K; k0 += 32) {
        async16(Ag0 + k0, &As[c0 * 8]);
        async16(Ag1 + k0, &As[c1 * 8]);
        async16(Bg0 + k0, &Bs[c0 * 8]);
        async16(Bg1 + k0, &Bs[c1 * 8]);
        __syncthreads();
        s16x8 af[4], bv[4];
        #pragma unroll
        for (int m = 0; m < 4; m++)
            af[m] = *(const s16x8*)&As[(wr * 64 + m * 16 + (lane & 15)) * 32 + (lane >> 4) * 8];
        #pragma unroll
        for (int n = 0; n < 4; n++)
            bv[n] = *(const s16x8*)&Bs[(wc * 64 + n * 16 + (lane & 15)) * 32 + (lane >> 4) * 8];
        #pragma unroll
        for (int m = 0; m < 4; m++)
            #pragma unroll
            for (int n = 0; n < 4; n++)
                acc[m][n] = __builtin_amdgcn_mfma_f32_16x16x32_bf16(af[m], bv[n], acc[m][n], 0, 0, 0);
        __syncthreads();
    }

    size_t cz = (size_t)blockIdx.z * sC;
    #pragma unroll
    for (int m = 0; m < 4; m++) {
        #pragma unroll
        for (int n = 0; n < 4; n++) {
            int col = bcol + wc * 64 + n * 16 + (lane & 15);
            float bvv = (EPI >= 1) ? bias[col] : 0.f;
            #pragma unroll
            for (int j = 0; j < 4; j++) {
                int row = brow + wr * 64 + m * 16 + (lane >> 4) * 4 + j;
                float v = acc[m][n][j] + bvv;
                if constexpr (EPI == 1) {
                    ((bf16_t*)Cptr)[cz + (size_t)row * Nc + col] = f2bf(fmaxf(v, 0.f));
                } else {
                    ((float*)Cptr)[cz + (size_t)row * Nc + col] = v;
                }
            }
        }
    }
}

// ---------------- softmax with scale+mask, fp32 in -> bf16 probs -------------
// one 256-thread block per row of 2048; covers G*CN rows, batch-aware mask.
__global__ __launch_bounds__(256) void softmax_kernel(
    const float* __restrict__ S, bf16_t* __restrict__ P,
    const float* __restrict__ mask, int bc0) {
    __shared__ float sm[4];
    int gr = blockIdx.x;
    int bc = bc0 + gr / CN;
    int b = bc / CC;
    const float* row = S + (size_t)gr * CN;
    const float* mrow = mask + (size_t)b * CN;
    int tid = threadIdx.x;
    float x[8];
    float mx = -3.4e38f;
    #pragma unroll
    for (int i = 0; i < 8; i++) {
        int idx = tid + i * 256;
        x[i] = row[idx] * SCALE - mrow[idx] * MASK_SCALE;
        mx = fmaxf(mx, x[i]);
    }
    mx = blockMax256(mx, sm);
    float s = 0.f;
    #pragma unroll
    for (int i = 0; i < 8; i++) {
        x[i] = __expf(x[i] - mx);
        s += x[i];
    }
    s = blockSum256(s, sm);
    float inv = 1.f / s;
    #pragma unroll
    for (int i = 0; i < 8; i++)
        P[(size_t)gr * CN + tid + i * 256] = f2bf(x[i] * inv);
}

// ---------------- residual + layernorm, E=512, one block per row -------------
__global__ __launch_bounds__(256) void ln_f32f32_bf16out(
    const float* __restrict__ a, const float* __restrict__ b,
    const float* __restrict__ g, const float* __restrict__ be,
    bf16_t* __restrict__ o) {
    __shared__ float sm[4];
    size_t base = (size_t)blockIdx.x * CE;
    int e0 = threadIdx.x, e1 = threadIdx.x + 256;
    float x0 = a[base + e0] + b[base + e0];
    float x1 = a[base + e1] + b[base + e1];
    float mu = blockSum256(x0 + x1, sm) * (1.f / CE);
    float d0 = x0 - mu, d1 = x1 - mu;
    float var = blockSum256(d0 * d0 + d1 * d1, sm) * (1.f / CE);
    float rs = rsqrtf(var + EPS);
    o[base + e0] = f2bf(d0 * rs * g[e0] + be[e0]);
    o[base + e1] = f2bf(d1 * rs * g[e1] + be[e1]);
}

__global__ __launch_bounds__(256) void ln_bf16f32_f32out(
    const bf16_t* __restrict__ a, const float* __restrict__ b,
    const float* __restrict__ g, const float* __restrict__ be,
    float* __restrict__ o) {
    __shared__ float sm[4];
    size_t base = (size_t)blockIdx.x * CE;
    int e0 = threadIdx.x, e1 = threadIdx.x + 256;
    float x0 = bf2f(a[base + e0]) + b[base + e0];
    float x1 = bf2f(a[base + e1]) + b[base + e1];
    float mu = blockSum256(x0 + x1, sm) * (1.f / CE);
    float d0 = x0 - mu, d1 = x1 - mu;
    float var = blockSum256(d0 * d0 + d1 * d1, sm) * (1.f / CE);
    float rs = rsqrtf(var + EPS);
    o[base + e0] = d0 * rs * g[e0] + be[e0];
    o[base + e1] = d1 * rs * g[e1] + be[e1];
}

// ---------------- host ----------------
extern "C" void kernel_launch(void* const* d_in, const int* in_sizes, int n_in,
                              void* d_out, int out_size, void* d_ws, size_t ws_size,
                              hipStream_t stream) {
    const float* src  = (const float*)d_in[0];
    const float* mask = (const float*)d_in[1];
    const float* W1   = (const float*)d_in[2];
    const float* b1   = (const float*)d_in[3];
    const float* W2   = (const float*)d_in[4];
    const float* b2   = (const float*)d_in[5];
    const float* g1   = (const float*)d_in[6];
    const float* be1  = (const float*)d_in[7];
    const float* g2   = (const float*)d_in[8];
    const float* be2  = (const float*)d_in[9];
    float* out = (float*)d_out;
    char* ws = (char*)d_ws;

    // ---- workspace carve (all sizes 256B-aligned naturally) ----
    size_t off = 0;
    auto carve = [&](size_t bytes) { char* p = ws + off; off += (bytes + 255) & ~(size_t)255; return p; };
    bf16_t* src_bf  = (bf16_t*)carve(TOT * 2);            // 64 MiB
    bf16_t* src2_bf = (bf16_t*)carve(TOT * 2);            // 64 MiB
    bf16_t* W1T     = (bf16_t*)carve((size_t)CE * CF * 2);
    bf16_t* W2T     = (bf16_t*)carve((size_t)CE * CF * 2);
    char* ph = ws + off;  // phase-shared region
    // attention phase layout:
    bf16_t* srcT   = (bf16_t*)(ph);                                         // G*E*N*2   =  8 MiB
    float*  scores = (float*)(ph + (size_t)G * CE * CN * 2);                // G*N*N*4   = 64 MiB
    bf16_t* probs  = (bf16_t*)(ph + (size_t)G * CE * CN * 2 + (size_t)G * CN * CN * 4);  // 32 MiB
    float*  attnO  = (float*)(ph + (size_t)G * CE * CN * 2 + (size_t)G * CN * CN * 4 + (size_t)G * CN * CN * 2);  // 16 MiB
    size_t attn_phase = (size_t)G * CE * CN * 2 + (size_t)G * CN * CN * 4 + (size_t)G * CN * CN * 2 + (size_t)G * CN * CE * 4;
    // FFN phase layout (reuses ph):
    bf16_t* H  = (bf16_t*)ph;                              // MCH*F*2 = 32 MiB
    float*  ff = (float*)(ph + (size_t)MCH * CF * 2);      // MCH*E*4 = 16 MiB
    size_t ffn_phase = (size_t)MCH * CF * 2 + (size_t)MCH * CE * 4;
    size_t need = off + (attn_phase > ffn_phase ? attn_phase : ffn_phase);
    if (ws_size < need) return;  // workspace too small: bail (output stays zero)

    // ---- pre-phase: conversions ----
    cvt_f32_bf16_vec<<<2048, 256, 0, stream>>>(src, src_bf, TOT);
    transpose_f32_bf16<<<dim3(CF / 32, CE / 32, 1), 256, 0, stream>>>(W1, W1T, CE, CF, 0, 0);
    transpose_f32_bf16<<<dim3(CE / 32, CF / 32, 1), 256, 0, stream>>>(W2, W2T, CF, CE, 0, 0);

    // ---- attention, groups of G batches ----
    for (int g0 = 0; g0 < CB * CC; g0 += G) {
        const float* srcf = src + (size_t)g0 * CN * CE;
        const bf16_t* srcb = src_bf + (size_t)g0 * CN * CE;
        transpose_f32_bf16<<<dim3(CE / 32, CN / 32, G), 256, 0, stream>>>(
            srcf, srcT, CN, CE, (long long)CN * CE, (long long)CE * CN);
        // S = Q @ K^T   [N,N] fp32
        gemm_bt<0><<<dim3(CN / 128, CN / 128, G), 256, 0, stream>>>(
            srcb, srcb, scores, nullptr, CN, CN, CE,
            (long long)CN * CE, (long long)CN * CE, (long long)CN * CN);
        softmax_kernel<<<dim3(G * CN), 256, 0, stream>>>(scores, probs, mask, g0);
        // O = P @ V  via  P [N,N] @ (V^T)[E,N]^T
        gemm_bt<0><<<dim3(CE / 128, CN / 128, G), 256, 0, stream>>>(
            probs, srcT, attnO, nullptr, CN, CE, CN,
            (long long)CN * CN, (long long)CE * CN, (long long)CN * CE);
        ln_f32f32_bf16out<<<dim3(G * CN), 256, 0, stream>>>(
            srcf, attnO, g1, be1, src2_bf + (size_t)g0 * CN * CE);
    }

    // ---- FFN + final LN, row chunks ----
    for (long long m0 = 0; m0 < (long long)CB * CC * CN; m0 += MCH) {
        const bf16_t* A2 = src2_bf + m0 * CE;
        gemm_bt<1><<<dim3(CF / 128, MCH / 128, 1), 256, 0, stream>>>(
            A2, W1T, H, b1, MCH, CF, CE, 0, 0, 0);
        gemm_bt<2><<<dim3(CE / 128, MCH / 128, 1), 256, 0, stream>>>(
            H, W2T, ff, b2, MCH, CE, CF, 0, 0, 0);
        ln_bf16f32_f32out<<<dim3(MCH), 256, 0, stream>>>(
            A2, ff, g2, be2, out + m0 * CE);
    }
}

// Round 2
// 1019.914 us; speedup vs baseline: 1.8005x; 1.8005x over previous
//
#include <hip/hip_runtime.h>
#include <stdint.h>

// ---------------- problem constants ----------------
constexpr int CB = 8, CC = 4, CN = 2048, CE = 512, CF = 2048;
constexpr long long TOT = (long long)CB * CC * CN * CE;   // 33,554,432 elems
constexpr int G = 4;          // attention batches per score-group
constexpr int MCH = 32768;    // FFN row chunk
constexpr float SCALE = 0.04419417382415922f;  // 1/sqrt(512)
constexpr float MASK_SCALE = 5.0f;
constexpr float EPS = 1e-5f;

typedef unsigned short bf16_t;
typedef __attribute__((ext_vector_type(4))) float f32x4;
typedef __attribute__((ext_vector_type(8))) short s16x8;

#define DEV static __device__ __forceinline__

DEV unsigned short f2bf(float f) {
    unsigned u = __float_as_uint(f);
    unsigned r = (u + 0x7fffu + ((u >> 16) & 1u)) >> 16;
    return (unsigned short)r;
}
DEV float bf2f(unsigned short b) {
    return __uint_as_float(((unsigned)b) << 16);
}

typedef const __attribute__((address_space(1))) unsigned int* gptr_t;
typedef __attribute__((address_space(3))) unsigned int* lptr_t;
DEV void async16(const void* g, void* l) {
    __builtin_amdgcn_global_load_lds((gptr_t)g, (lptr_t)l, 16, 0, 0);
}

#define FULL_BAR() do { asm volatile("" ::: "memory"); __builtin_amdgcn_s_barrier(); asm volatile("" ::: "memory"); } while (0)
#define LGKM0() asm volatile("s_waitcnt lgkmcnt(0)" ::: "memory")

// ---------------- reductions (256-thread blocks = 4 waves) ----------------
DEV float blockSum256(float v, float* sm) {
    #pragma unroll
    for (int o = 32; o; o >>= 1) v += __shfl_xor(v, o);
    int w = threadIdx.x >> 6;
    __syncthreads();
    if ((threadIdx.x & 63) == 0) sm[w] = v;
    __syncthreads();
    return sm[0] + sm[1] + sm[2] + sm[3];
}
DEV float blockMax256(float v, float* sm) {
    #pragma unroll
    for (int o = 32; o; o >>= 1) v = fmaxf(v, __shfl_xor(v, o));
    int w = threadIdx.x >> 6;
    __syncthreads();
    if ((threadIdx.x & 63) == 0) sm[w] = v;
    __syncthreads();
    return fmaxf(fmaxf(sm[0], sm[1]), fmaxf(sm[2], sm[3]));
}

// ---------------- fp32 -> bf16 convert ----------------
__global__ __launch_bounds__(256) void cvt_f32_bf16_vec(
    const float* __restrict__ in, bf16_t* __restrict__ out, long long n) {
    long long i = ((long long)blockIdx.x * 256 + threadIdx.x) * 4;
    long long stride = (long long)gridDim.x * 1024;
    for (; i < n; i += stride) {
        float4 v = *reinterpret_cast<const float4*>(in + i);
        ushort4 u;
        u.x = f2bf(v.x); u.y = f2bf(v.y); u.z = f2bf(v.z); u.w = f2bf(v.w);
        *reinterpret_cast<ushort4*>(out + i) = u;
    }
}

// ---------------- transpose fp32[R][C] -> bf16[C][R] (weights) ----------------
__global__ __launch_bounds__(256) void transpose_f32_bf16(
    const float* __restrict__ in, bf16_t* __restrict__ out,
    int R, int Cc) {
    __shared__ float tile[32][33];
    int rb = blockIdx.y * 32, cb = blockIdx.x * 32;
    int tx = threadIdx.x & 31, ty = threadIdx.x >> 5;  // ty 0..7
    #pragma unroll
    for (int i = 0; i < 32; i += 8)
        tile[ty + i][tx] = in[(size_t)(rb + ty + i) * Cc + cb + tx];
    __syncthreads();
    #pragma unroll
    for (int i = 0; i < 32; i += 8)
        out[(size_t)(cb + ty + i) * R + rb + tx] = f2bf(tile[tx][ty + i]);
}

// ---------------- transpose bf16[R][C] -> bf16[C][R], batched via z ----------------
__global__ __launch_bounds__(256) void transpose_bf16(
    const bf16_t* __restrict__ in, bf16_t* __restrict__ out,
    int R, int Cc, long long sIn, long long sOut) {
    __shared__ bf16_t tile[32][36];
    const bf16_t* inz = in + (size_t)blockIdx.z * sIn;
    bf16_t* outz = out + (size_t)blockIdx.z * sOut;
    int rb = blockIdx.y * 32, cb = blockIdx.x * 32;
    int t = threadIdx.x;
    int r = t >> 3, c4 = (t & 7) * 4;
    *(ushort4*)&tile[r][c4] = *(const ushort4*)&inz[(size_t)(rb + r) * Cc + cb + c4];
    __syncthreads();
    int c = t >> 3, r4 = (t & 7) * 4;
    ushort4 w;
    w.x = tile[r4 + 0][c]; w.y = tile[r4 + 1][c];
    w.z = tile[r4 + 2][c]; w.w = tile[r4 + 3][c];
    *(ushort4*)&outz[(size_t)(cb + c) * R + rb + r4] = w;
}

// ============ 256x256 8-phase GEMM: C[M,Nc] = A[M,K] @ B[Nc,K]^T ============
// bf16 in, fp32 acc. 8 waves (2Mx4N), BK=64, 128KiB dyn LDS double-buffered.
// XOR swizzle: logical (row, kslot s) stored at slot s^(row&7) (16B slots).
// EPI 0: fp32 store. 1: +bias relu bf16. 2: +bias fp32. 3: bf16.
template <int EPI>
__global__ __launch_bounds__(512, 2) void gemm256(
    const bf16_t* __restrict__ A, const bf16_t* __restrict__ B,
    void* __restrict__ Cptr, const float* __restrict__ bias,
    int M, int Nc, int K, long long sA, long long sB, long long sC) {
    extern __shared__ bf16_t lds[];
    bf16_t* AsL = lds;           // [dbuf2][half2][128*64]
    bf16_t* BsL = lds + 32768;
    const bf16_t* Az = A + (size_t)blockIdx.z * sA;
    const bf16_t* Bz = B + (size_t)blockIdx.z * sB;
    const int t = threadIdx.x;
    const int lane = t & 63, wid = t >> 6;
    const int wr = wid >> 2, wc = wid & 3;
    const int brow = blockIdx.y * 256, bcol = blockIdx.x * 256;
    const int NT = K >> 6;

    // staging precompute: seg0 = t (rows 0-63), seg1 = t+512 (rows 64-127)
    const int r0 = t >> 3, s0 = t & 7;
    const int ce = ((s0 ^ (r0 & 7)) << 3);      // pre-swizzled source col (elems)
    const bf16_t* aP0 = Az + (size_t)(brow + r0) * K + ce;
    const bf16_t* bP0 = Bz + (size_t)(bcol + r0) * K + ce;
    const size_t rK64 = (size_t)64 * K;
    const size_t h128K = (size_t)128 * K;

    #define STAGE_A(kt_, h_) do { \
        bf16_t* d_ = AsL + ((((kt_) & 1) * 2 + (h_)) * 8192); \
        const bf16_t* s_ = aP0 + (size_t)(h_) * h128K + (size_t)(kt_) * 64; \
        async16(s_, d_ + t * 8); \
        async16(s_ + rK64, d_ + 4096 + t * 8); \
    } while (0)
    #define STAGE_B(kt_, h_) do { \
        bf16_t* d_ = BsL + ((((kt_) & 1) * 2 + (h_)) * 8192); \
        const bf16_t* s_ = bP0 + (size_t)(h_) * h128K + (size_t)(kt_) * 64; \
        async16(s_, d_ + t * 8); \
        async16(s_ + rK64, d_ + 4096 + t * 8); \
    } while (0)

    // fragment read addressing
    const int q = lane >> 4, rr0 = lane & 15, xmask = rr0 & 7;
    s16x8 af[4][2];          // current qm A-frags
    s16x8 bv[2][2][2];       // [qn][n][ks] B-frags (whole K-tile resident)
    f32x4 acc[2][2][4][2] = {};

    #define READ_A(ktp_, qm_) do { \
        const bf16_t* base_ = AsL + (((ktp_) * 2 + (qm_)) * 8192); \
        _Pragma("unroll") for (int m_ = 0; m_ < 4; ++m_) \
        _Pragma("unroll") for (int ks_ = 0; ks_ < 2; ++ks_) \
            af[m_][ks_] = *(const s16x8*)(base_ + (wr * 64 + m_ * 16 + rr0) * 64 + (((ks_ * 4 + q) ^ xmask) << 3)); \
    } while (0)
    #define READ_B(ktp_, qn_) do { \
        const bf16_t* base_ = BsL + (((ktp_) * 2 + (qn_)) * 8192); \
        _Pragma("unroll") for (int n_ = 0; n_ < 2; ++n_) \
        _Pragma("unroll") for (int ks_ = 0; ks_ < 2; ++ks_) \
            bv[qn_][n_][ks_] = *(const s16x8*)(base_ + (wc * 32 + n_ * 16 + rr0) * 64 + (((ks_ * 4 + q) ^ xmask) << 3)); \
    } while (0)
    #define MFMA_Q(qm_, qn_) do { \
        __builtin_amdgcn_s_setprio(1); \
        _Pragma("unroll") for (int m_ = 0; m_ < 4; ++m_) \
        _Pragma("unroll") for (int n_ = 0; n_ < 2; ++n_) \
        _Pragma("unroll") for (int ks_ = 0; ks_ < 2; ++ks_) \
            acc[qm_][qn_][m_][n_] = __builtin_amdgcn_mfma_f32_16x16x32_bf16( \
                af[m_][ks_], bv[qn_][n_][ks_], acc[qm_][qn_][m_][n_], 0, 0, 0); \
        __builtin_amdgcn_s_setprio(0); \
    } while (0)

    // ---- prologue: stage K-tile 0 fully + A0/B0 of K-tile 1 ----
    STAGE_A(0, 0); STAGE_B(0, 0); STAGE_B(0, 1); STAGE_A(0, 1);
    if (1 < NT) {
        STAGE_A(1, 0); STAGE_B(1, 0);
        asm volatile("s_waitcnt vmcnt(4)" ::: "memory");
    } else {
        asm volatile("s_waitcnt vmcnt(0)" ::: "memory");
    }
    FULL_BAR();

    for (int kt = 0; kt < NT; ++kt) {
        const int ktp = kt & 1;
        // ---- phase 0: quadrant (0,0) ----
        READ_A(ktp, 0);
        READ_B(ktp, 0);
        if (kt + 1 < NT) STAGE_B(kt + 1, 1);
        FULL_BAR();
        LGKM0();
        MFMA_Q(0, 0);
        FULL_BAR();
        // ---- phase 1: quadrant (0,1) ----
        READ_B(ktp, 1);
        if (kt + 1 < NT) STAGE_A(kt + 1, 1);
        FULL_BAR();
        LGKM0();
        MFMA_Q(0, 1);
        FULL_BAR();
        // ---- phase 2: quadrant (1,0) ----
        READ_A(ktp, 1);
        if (kt + 2 < NT) STAGE_A(kt + 2, 0);
        FULL_BAR();
        LGKM0();
        MFMA_Q(1, 0);
        FULL_BAR();
        // ---- phase 3: quadrant (1,1) ----
        if (kt + 2 < NT) {
            STAGE_B(kt + 2, 0);
            asm volatile("s_waitcnt vmcnt(4)" ::: "memory");
        } else {
            asm volatile("s_waitcnt vmcnt(0)" ::: "memory");
        }
        FULL_BAR();
        MFMA_Q(1, 1);
        FULL_BAR();
    }

    // ---- epilogue ----
    size_t cz = (size_t)blockIdx.z * sC;
    #pragma unroll
    for (int qm = 0; qm < 2; ++qm)
    #pragma unroll
    for (int qn = 0; qn < 2; ++qn)
    #pragma unroll
    for (int m = 0; m < 4; ++m)
    #pragma unroll
    for (int n = 0; n < 2; ++n) {
        int col = bcol + qn * 128 + wc * 32 + n * 16 + (lane & 15);
        float bvv = (EPI == 1 || EPI == 2) ? bias[col] : 0.f;
        #pragma unroll
        for (int j = 0; j < 4; ++j) {
            int row = brow + qm * 128 + wr * 64 + m * 16 + q * 4 + j;
            float v = acc[qm][qn][m][n][j] + bvv;
            if constexpr (EPI == 1)
                ((bf16_t*)Cptr)[cz + (size_t)row * Nc + col] = f2bf(fmaxf(v, 0.f));
            else if constexpr (EPI == 3)
                ((bf16_t*)Cptr)[cz + (size_t)row * Nc + col] = f2bf(v);
            else
                ((float*)Cptr)[cz + (size_t)row * Nc + col] = v;
        }
    }
    #undef STAGE_A
    #undef STAGE_B
    #undef READ_A
    #undef READ_B
    #undef MFMA_Q
}

// ---------------- softmax with scale+mask, fp32 in -> bf16 probs -------------
__global__ __launch_bounds__(256) void softmax_kernel(
    const float* __restrict__ S, bf16_t* __restrict__ P,
    const float* __restrict__ mask, int bc0) {
    __shared__ float sm[4];
    int gr = blockIdx.x;
    int bc = bc0 + gr / CN;
    int b = bc / CC;
    const float* row = S + (size_t)gr * CN;
    const float* mrow = mask + (size_t)b * CN;
    int tid = threadIdx.x;
    float4 v0 = *(const float4*)&row[tid * 4];
    float4 v1 = *(const float4*)&row[1024 + tid * 4];
    float4 m0 = *(const float4*)&mrow[tid * 4];
    float4 m1 = *(const float4*)&mrow[1024 + tid * 4];
    float x[8];
    x[0] = v0.x * SCALE - m0.x * MASK_SCALE; x[1] = v0.y * SCALE - m0.y * MASK_SCALE;
    x[2] = v0.z * SCALE - m0.z * MASK_SCALE; x[3] = v0.w * SCALE - m0.w * MASK_SCALE;
    x[4] = v1.x * SCALE - m1.x * MASK_SCALE; x[5] = v1.y * SCALE - m1.y * MASK_SCALE;
    x[6] = v1.z * SCALE - m1.z * MASK_SCALE; x[7] = v1.w * SCALE - m1.w * MASK_SCALE;
    float mx = -3.4e38f;
    #pragma unroll
    for (int i = 0; i < 8; i++) mx = fmaxf(mx, x[i]);
    mx = blockMax256(mx, sm);
    float s = 0.f;
    #pragma unroll
    for (int i = 0; i < 8; i++) { x[i] = __expf(x[i] - mx); s += x[i]; }
    s = blockSum256(s, sm);
    float inv = 1.f / s;
    ushort4 u0, u1;
    u0.x = f2bf(x[0] * inv); u0.y = f2bf(x[1] * inv);
    u0.z = f2bf(x[2] * inv); u0.w = f2bf(x[3] * inv);
    u1.x = f2bf(x[4] * inv); u1.y = f2bf(x[5] * inv);
    u1.z = f2bf(x[6] * inv); u1.w = f2bf(x[7] * inv);
    *(ushort4*)&P[(size_t)gr * CN + tid * 4] = u0;
    *(ushort4*)&P[(size_t)gr * CN + 1024 + tid * 4] = u1;
}

// ---------------- residual + layernorm kernels (E=512, one block/row) --------
__global__ __launch_bounds__(256) void ln1_kernel(
    const float* __restrict__ src, const bf16_t* __restrict__ ao,
    const float* __restrict__ g, const float* __restrict__ be,
    bf16_t* __restrict__ o) {
    __shared__ float sm[4];
    size_t base = (size_t)blockIdx.x * CE;
    int e = threadIdx.x * 2;
    float2 s = *(const float2*)&src[base + e];
    ushort2 a = *(const ushort2*)&ao[base + e];
    float x0 = s.x + bf2f(a.x), x1 = s.y + bf2f(a.y);
    float mu = blockSum256(x0 + x1, sm) * (1.f / CE);
    float d0 = x0 - mu, d1 = x1 - mu;
    float var = blockSum256(d0 * d0 + d1 * d1, sm) * (1.f / CE);
    float rs = rsqrtf(var + EPS);
    ushort2 w;
    w.x = f2bf(d0 * rs * g[e] + be[e]);
    w.y = f2bf(d1 * rs * g[e + 1] + be[e + 1]);
    *(ushort2*)&o[base + e] = w;
}

__global__ __launch_bounds__(256) void ln2_kernel(
    const bf16_t* __restrict__ a, const float* __restrict__ b,
    const float* __restrict__ g, const float* __restrict__ be,
    float* __restrict__ o) {
    __shared__ float sm[4];
    size_t base = (size_t)blockIdx.x * CE;
    int e = threadIdx.x * 2;
    ushort2 aa = *(const ushort2*)&a[base + e];
    float2 bb = *(const float2*)&b[base + e];
    float x0 = bf2f(aa.x) + bb.x, x1 = bf2f(aa.y) + bb.y;
    float mu = blockSum256(x0 + x1, sm) * (1.f / CE);
    float d0 = x0 - mu, d1 = x1 - mu;
    float var = blockSum256(d0 * d0 + d1 * d1, sm) * (1.f / CE);
    float rs = rsqrtf(var + EPS);
    float2 w;
    w.x = d0 * rs * g[e] + be[e];
    w.y = d1 * rs * g[e + 1] + be[e + 1];
    *(float2*)&o[base + e] = w;
}

// ---------------- host ----------------
extern "C" void kernel_launch(void* const* d_in, const int* in_sizes, int n_in,
                              void* d_out, int out_size, void* d_ws, size_t ws_size,
                              hipStream_t stream) {
    const float* src  = (const float*)d_in[0];
    const float* mask = (const float*)d_in[1];
    const float* W1   = (const float*)d_in[2];
    const float* b1   = (const float*)d_in[3];
    const float* W2   = (const float*)d_in[4];
    const float* b2   = (const float*)d_in[5];
    const float* g1   = (const float*)d_in[6];
    const float* be1  = (const float*)d_in[7];
    const float* g2   = (const float*)d_in[8];
    const float* be2  = (const float*)d_in[9];
    float* out = (float*)d_out;
    char* ws = (char*)d_ws;

    // 128KiB dynamic LDS opt-in (host-side, not a stream op; idempotent)
    hipFuncSetAttribute(reinterpret_cast<const void*>(&gemm256<0>), hipFuncAttributeMaxDynamicSharedMemorySize, 131072);
    hipFuncSetAttribute(reinterpret_cast<const void*>(&gemm256<1>), hipFuncAttributeMaxDynamicSharedMemorySize, 131072);
    hipFuncSetAttribute(reinterpret_cast<const void*>(&gemm256<2>), hipFuncAttributeMaxDynamicSharedMemorySize, 131072);
    hipFuncSetAttribute(reinterpret_cast<const void*>(&gemm256<3>), hipFuncAttributeMaxDynamicSharedMemorySize, 131072);

    // ---- workspace layout (MiB offsets) ----
    // [0,256)   probs (bf16, all 32)   | after PV: [0,64)=src2, [64,128)=ff
    // [256,320) src_bf                 | FFN: H[0:64MB)
    // [320,384) srcT                   | FFN: H[64:128MB)
    // [384,448) scores (fp32, G=4)     | after softmax: attnO (bf16, all 32)
    // [448,452) W1T, W2T
    const size_t MB = 1024 * 1024;
    bf16_t* probs  = (bf16_t*)(ws);
    bf16_t* src_bf = (bf16_t*)(ws + 256 * MB);
    bf16_t* srcT   = (bf16_t*)(ws + 320 * MB);
    float*  scores = (float*)(ws + 384 * MB);
    bf16_t* W1T    = (bf16_t*)(ws + 448 * MB);
    bf16_t* W2T    = (bf16_t*)(ws + 450 * MB);
    bf16_t* attnO  = (bf16_t*)(ws + 384 * MB);   // overlays scores
    bf16_t* src2   = (bf16_t*)(ws);              // overlays probs head
    float*  ff     = (float*)(ws + 64 * MB);     // overlays probs[64:128MB)
    bf16_t* H      = (bf16_t*)(ws + 256 * MB);   // overlays src_bf+srcT
    if (ws_size < 452 * MB) return;

    // ---- conversions ----
    cvt_f32_bf16_vec<<<4096, 256, 0, stream>>>(src, src_bf, TOT);
    transpose_f32_bf16<<<dim3(CF / 32, CE / 32, 1), 256, 0, stream>>>(W1, W1T, CE, CF);
    transpose_f32_bf16<<<dim3(CE / 32, CF / 32, 1), 256, 0, stream>>>(W2, W2T, CF, CE);
    transpose_bf16<<<dim3(CE / 32, CN / 32, 32), 256, 0, stream>>>(
        src_bf, srcT, CN, CE, (long long)CN * CE, (long long)CE * CN);

    // ---- attention scores + softmax, groups of G batches ----
    for (int g0 = 0; g0 < CB * CC; g0 += G) {
        const bf16_t* srcb = src_bf + (size_t)g0 * CN * CE;
        gemm256<0><<<dim3(CN / 256, CN / 256, G), 512, 131072, stream>>>(
            srcb, srcb, scores, nullptr, CN, CN, CE,
            (long long)CN * CE, (long long)CN * CE, (long long)CN * CN);
        softmax_kernel<<<dim3(G * CN), 256, 0, stream>>>(
            scores, probs + (size_t)g0 * CN * CN, mask, g0);
    }
    // ---- PV (all 32 batches) + residual/LN1 ----
    gemm256<3><<<dim3(CE / 256, CN / 256, 32), 512, 131072, stream>>>(
        probs, srcT, attnO, nullptr, CN, CE, CN,
        (long long)CN * CN, (long long)CE * CN, (long long)CN * CE);
    ln1_kernel<<<dim3(CB * CC * CN), 256, 0, stream>>>(src, attnO, g1, be1, src2);

    // ---- FFN + final LN, 2 chunks ----
    for (int c = 0; c < 2; ++c) {
        const bf16_t* A2 = src2 + (size_t)c * MCH * CE;
        gemm256<1><<<dim3(CF / 256, MCH / 256, 1), 512, 131072, stream>>>(
            A2, W1T, H, b1, MCH, CF, CE, 0, 0, 0);
        gemm256<2><<<dim3(CE / 256, MCH / 256, 1), 512, 131072, stream>>>(
            H, W2T, ff, b2, MCH, CE, CF, 0, 0, 0);
        ln2_kernel<<<dim3(MCH), 256, 0, stream>>>(
            A2, ff, g2, be2, out + (size_t)c * MCH * CE);
    }
}

// Round 3
// 904.834 us; speedup vs baseline: 2.0294x; 1.1272x over previous
//
#include <hip/hip_runtime.h>
#include <stdint.h>

// ---------------- problem constants ----------------
constexpr int CB = 8, CC = 4, CN = 2048, CE = 512, CF = 2048;
constexpr long long TOT = (long long)CB * CC * CN * CE;
constexpr int MCH = 32768;    // FFN row chunk
constexpr float SCALE = 0.04419417382415922f;  // 1/sqrt(512)
constexpr float MASK_SCALE = 5.0f;
constexpr float EPS = 1e-5f;

typedef unsigned short bf16_t;
typedef __attribute__((ext_vector_type(4))) float f32x4;
typedef __attribute__((ext_vector_type(8))) short s16x8;

#define DEV static __device__ __forceinline__

DEV unsigned short f2bf(float f) {
    unsigned u = __float_as_uint(f);
    unsigned r = (u + 0x7fffu + ((u >> 16) & 1u)) >> 16;
    return (unsigned short)r;
}
DEV float bf2f(unsigned short b) {
    return __uint_as_float(((unsigned)b) << 16);
}

typedef const __attribute__((address_space(1))) unsigned int* gptr_t;
typedef __attribute__((address_space(3))) unsigned int* lptr_t;
DEV void async16(const void* g, void* l) {
    __builtin_amdgcn_global_load_lds((gptr_t)g, (lptr_t)l, 16, 0, 0);
}

#define FULL_BAR() do { asm volatile("" ::: "memory"); __builtin_amdgcn_s_barrier(); asm volatile("" ::: "memory"); } while (0)
#define LGKM0() asm volatile("s_waitcnt lgkmcnt(0)" ::: "memory")

// ---------------- reductions (256-thread blocks = 4 waves) ----------------
DEV float blockSum256(float v, float* sm) {
    #pragma unroll
    for (int o = 32; o; o >>= 1) v += __shfl_xor(v, o);
    int w = threadIdx.x >> 6;
    __syncthreads();
    if ((threadIdx.x & 63) == 0) sm[w] = v;
    __syncthreads();
    return sm[0] + sm[1] + sm[2] + sm[3];
}
DEV float blockMax256(float v, float* sm) {
    #pragma unroll
    for (int o = 32; o; o >>= 1) v = fmaxf(v, __shfl_xor(v, o));
    int w = threadIdx.x >> 6;
    __syncthreads();
    if ((threadIdx.x & 63) == 0) sm[w] = v;
    __syncthreads();
    return fmaxf(fmaxf(sm[0], sm[1]), fmaxf(sm[2], sm[3]));
}

// ---------------- fp32 -> bf16 convert ----------------
__global__ __launch_bounds__(256) void cvt_f32_bf16_vec(
    const float* __restrict__ in, bf16_t* __restrict__ out, long long n) {
    long long i = ((long long)blockIdx.x * 256 + threadIdx.x) * 4;
    long long stride = (long long)gridDim.x * 1024;
    for (; i < n; i += stride) {
        float4 v = *reinterpret_cast<const float4*>(in + i);
        ushort4 u;
        u.x = f2bf(v.x); u.y = f2bf(v.y); u.z = f2bf(v.z); u.w = f2bf(v.w);
        *reinterpret_cast<ushort4*>(out + i) = u;
    }
}

// ---------------- transpose fp32[R][C] -> bf16[C][R] (weights) ----------------
__global__ __launch_bounds__(256) void transpose_f32_bf16(
    const float* __restrict__ in, bf16_t* __restrict__ out,
    int R, int Cc) {
    __shared__ float tile[32][33];
    int rb = blockIdx.y * 32, cb = blockIdx.x * 32;
    int tx = threadIdx.x & 31, ty = threadIdx.x >> 5;
    #pragma unroll
    for (int i = 0; i < 32; i += 8)
        tile[ty + i][tx] = in[(size_t)(rb + ty + i) * Cc + cb + tx];
    __syncthreads();
    #pragma unroll
    for (int i = 0; i < 32; i += 8)
        out[(size_t)(cb + ty + i) * R + rb + tx] = f2bf(tile[tx][ty + i]);
}

// ---------------- transpose bf16[R][C] -> bf16[C][R], batched via z ----------------
__global__ __launch_bounds__(256) void transpose_bf16(
    const bf16_t* __restrict__ in, bf16_t* __restrict__ out,
    int R, int Cc, long long sIn, long long sOut) {
    __shared__ bf16_t tile[32][36];
    const bf16_t* inz = in + (size_t)blockIdx.z * sIn;
    bf16_t* outz = out + (size_t)blockIdx.z * sOut;
    int rb = blockIdx.y * 32, cb = blockIdx.x * 32;
    int t = threadIdx.x;
    int r = t >> 3, c4 = (t & 7) * 4;
    *(ushort4*)&tile[r][c4] = *(const ushort4*)&inz[(size_t)(rb + r) * Cc + cb + c4];
    __syncthreads();
    int c = t >> 3, r4 = (t & 7) * 4;
    ushort4 w;
    w.x = tile[r4 + 0][c]; w.y = tile[r4 + 1][c];
    w.z = tile[r4 + 2][c]; w.w = tile[r4 + 3][c];
    *(ushort4*)&outz[(size_t)(cb + c) * R + rb + r4] = w;
}

// ============ 256x256 8-phase GEMM: C[M,Nc] = A[M,K] @ B[Nc,K]^T ============
// bf16 in, fp32 acc. 8 waves (2Mx4N), BK=64, 128KiB dyn LDS double-buffered.
// XOR swizzle on 16B k-slots; XCD-aware bijective block swizzle (nwg%8==0).
// EPI 0: fp32. 1: +bias relu bf16. 2: +bias fp32. 3: alpha*bf16.
template <int EPI>
__global__ __launch_bounds__(512, 2) void gemm256(
    const bf16_t* __restrict__ A, const bf16_t* __restrict__ B,
    void* __restrict__ Cptr, const float* __restrict__ bias, float alpha,
    int M, int Nc, int K, long long sA, long long sB, long long sC) {
    extern __shared__ bf16_t lds[];
    bf16_t* AsL = lds;           // [dbuf2][half2][128*64]
    bf16_t* BsL = lds + 32768;

    // ---- XCD-aware bijective swizzle (requires nwg % 8 == 0) ----
    int bx, by, bz;
    {
        int gx = gridDim.x, gy = gridDim.y;
        int nwg = gx * gy * gridDim.z;
        int flat = blockIdx.x + gx * (blockIdx.y + gy * blockIdx.z);
        int wg = (nwg & 7) ? flat : ((flat & 7) * (nwg >> 3) + (flat >> 3));
        bx = wg % gx;
        int tmp = wg / gx;
        by = tmp % gy;
        bz = tmp / gy;
    }

    const bf16_t* Az = A + (size_t)bz * sA;
    const bf16_t* Bz = B + (size_t)bz * sB;
    const int t = threadIdx.x;
    const int lane = t & 63, wid = t >> 6;
    const int wr = wid >> 2, wc = wid & 3;
    const int brow = by * 256, bcol = bx * 256;
    const int NT = K >> 6;

    const int r0 = t >> 3, s0 = t & 7;
    const int ce = ((s0 ^ (r0 & 7)) << 3);      // pre-swizzled source col (elems)
    const bf16_t* aP0 = Az + (size_t)(brow + r0) * K + ce;
    const bf16_t* bP0 = Bz + (size_t)(bcol + r0) * K + ce;
    const size_t rK64 = (size_t)64 * K;
    const size_t h128K = (size_t)128 * K;

    #define STAGE_A(kt_, h_) do { \
        bf16_t* d_ = AsL + ((((kt_) & 1) * 2 + (h_)) * 8192); \
        const bf16_t* s_ = aP0 + (size_t)(h_) * h128K + (size_t)(kt_) * 64; \
        async16(s_, d_ + t * 8); \
        async16(s_ + rK64, d_ + 4096 + t * 8); \
    } while (0)
    #define STAGE_B(kt_, h_) do { \
        bf16_t* d_ = BsL + ((((kt_) & 1) * 2 + (h_)) * 8192); \
        const bf16_t* s_ = bP0 + (size_t)(h_) * h128K + (size_t)(kt_) * 64; \
        async16(s_, d_ + t * 8); \
        async16(s_ + rK64, d_ + 4096 + t * 8); \
    } while (0)

    const int q = lane >> 4, rr0 = lane & 15, xmask = rr0 & 7;
    s16x8 af[4][2];
    s16x8 bv[2][2][2];
    f32x4 acc[2][2][4][2] = {};

    #define READ_A(ktp_, qm_) do { \
        const bf16_t* base_ = AsL + (((ktp_) * 2 + (qm_)) * 8192); \
        _Pragma("unroll") for (int m_ = 0; m_ < 4; ++m_) \
        _Pragma("unroll") for (int ks_ = 0; ks_ < 2; ++ks_) \
            af[m_][ks_] = *(const s16x8*)(base_ + (wr * 64 + m_ * 16 + rr0) * 64 + (((ks_ * 4 + q) ^ xmask) << 3)); \
    } while (0)
    #define READ_B(ktp_, qn_) do { \
        const bf16_t* base_ = BsL + (((ktp_) * 2 + (qn_)) * 8192); \
        _Pragma("unroll") for (int n_ = 0; n_ < 2; ++n_) \
        _Pragma("unroll") for (int ks_ = 0; ks_ < 2; ++ks_) \
            bv[qn_][n_][ks_] = *(const s16x8*)(base_ + (wc * 32 + n_ * 16 + rr0) * 64 + (((ks_ * 4 + q) ^ xmask) << 3)); \
    } while (0)
    #define MFMA_Q(qm_, qn_) do { \
        __builtin_amdgcn_s_setprio(1); \
        _Pragma("unroll") for (int m_ = 0; m_ < 4; ++m_) \
        _Pragma("unroll") for (int n_ = 0; n_ < 2; ++n_) \
        _Pragma("unroll") for (int ks_ = 0; ks_ < 2; ++ks_) \
            acc[qm_][qn_][m_][n_] = __builtin_amdgcn_mfma_f32_16x16x32_bf16( \
                af[m_][ks_], bv[qn_][n_][ks_], acc[qm_][qn_][m_][n_], 0, 0, 0); \
        __builtin_amdgcn_s_setprio(0); \
    } while (0)

    // ---- prologue ----
    STAGE_A(0, 0); STAGE_B(0, 0); STAGE_B(0, 1); STAGE_A(0, 1);
    if (1 < NT) {
        STAGE_A(1, 0); STAGE_B(1, 0);
        asm volatile("s_waitcnt vmcnt(4)" ::: "memory");
    } else {
        asm volatile("s_waitcnt vmcnt(0)" ::: "memory");
    }
    FULL_BAR();

    for (int kt = 0; kt < NT; ++kt) {
        const int ktp = kt & 1;
        READ_A(ktp, 0);
        READ_B(ktp, 0);
        if (kt + 1 < NT) STAGE_B(kt + 1, 1);
        FULL_BAR();
        LGKM0();
        MFMA_Q(0, 0);
        FULL_BAR();

        READ_B(ktp, 1);
        if (kt + 1 < NT) STAGE_A(kt + 1, 1);
        FULL_BAR();
        LGKM0();
        MFMA_Q(0, 1);
        FULL_BAR();

        READ_A(ktp, 1);
        if (kt + 2 < NT) STAGE_A(kt + 2, 0);
        FULL_BAR();
        LGKM0();
        MFMA_Q(1, 0);
        FULL_BAR();

        if (kt + 2 < NT) {
            STAGE_B(kt + 2, 0);
            asm volatile("s_waitcnt vmcnt(4)" ::: "memory");
        } else {
            asm volatile("s_waitcnt vmcnt(0)" ::: "memory");
        }
        FULL_BAR();
        MFMA_Q(1, 1);
        FULL_BAR();
    }

    // ---- epilogue ----
    size_t cz = (size_t)bz * sC;
    #pragma unroll
    for (int qm = 0; qm < 2; ++qm)
    #pragma unroll
    for (int qn = 0; qn < 2; ++qn)
    #pragma unroll
    for (int m = 0; m < 4; ++m)
    #pragma unroll
    for (int n = 0; n < 2; ++n) {
        int col = bcol + qn * 128 + wc * 32 + n * 16 + (lane & 15);
        float bvv = (EPI == 1 || EPI == 2) ? bias[col] : 0.f;
        #pragma unroll
        for (int j = 0; j < 4; ++j) {
            int row = brow + qm * 128 + wr * 64 + m * 16 + q * 4 + j;
            float v = acc[qm][qn][m][n][j] + bvv;
            if constexpr (EPI == 1)
                ((bf16_t*)Cptr)[cz + (size_t)row * Nc + col] = f2bf(fmaxf(v, 0.f));
            else if constexpr (EPI == 3)
                ((bf16_t*)Cptr)[cz + (size_t)row * Nc + col] = f2bf(v * alpha);
            else
                ((float*)Cptr)[cz + (size_t)row * Nc + col] = v;
        }
    }
    #undef STAGE_A
    #undef STAGE_B
    #undef READ_A
    #undef READ_B
    #undef MFMA_Q
}

// ---------------- softmax: bf16 scores (pre-scaled) in-place -> bf16 probs ---
// one block per row; mask subtracted here. gr = bc*CN + n; b = gr >> 13.
__global__ __launch_bounds__(256) void softmax_bf16(
    bf16_t* __restrict__ S, const float* __restrict__ mask) {
    __shared__ float sm[4];
    int gr = blockIdx.x;
    int b = gr >> 13;
    bf16_t* row = S + (size_t)gr * CN;
    int tid = threadIdx.x;
    const float* mrow = mask + (size_t)b * CN + tid * 8;
    s16x8 v = *(const s16x8*)(row + tid * 8);
    float4 m0 = *(const float4*)(mrow);
    float4 m1 = *(const float4*)(mrow + 4);
    float x[8];
    x[0] = bf2f((unsigned short)v[0]) - m0.x * MASK_SCALE;
    x[1] = bf2f((unsigned short)v[1]) - m0.y * MASK_SCALE;
    x[2] = bf2f((unsigned short)v[2]) - m0.z * MASK_SCALE;
    x[3] = bf2f((unsigned short)v[3]) - m0.w * MASK_SCALE;
    x[4] = bf2f((unsigned short)v[4]) - m1.x * MASK_SCALE;
    x[5] = bf2f((unsigned short)v[5]) - m1.y * MASK_SCALE;
    x[6] = bf2f((unsigned short)v[6]) - m1.z * MASK_SCALE;
    x[7] = bf2f((unsigned short)v[7]) - m1.w * MASK_SCALE;
    float mx = -3.4e38f;
    #pragma unroll
    for (int i = 0; i < 8; i++) mx = fmaxf(mx, x[i]);
    mx = blockMax256(mx, sm);
    float s = 0.f;
    #pragma unroll
    for (int i = 0; i < 8; i++) { x[i] = __expf(x[i] - mx); s += x[i]; }
    s = blockSum256(s, sm);
    float inv = 1.f / s;
    s16x8 u;
    #pragma unroll
    for (int i = 0; i < 8; i++) u[i] = (short)f2bf(x[i] * inv);
    *(s16x8*)(row + tid * 8) = u;
}

// ---------------- residual + layernorm kernels (E=512, one block/row) --------
__global__ __launch_bounds__(256) void ln1_kernel(
    const bf16_t* __restrict__ src, const bf16_t* __restrict__ ao,
    const float* __restrict__ g, const float* __restrict__ be,
    bf16_t* __restrict__ o) {
    __shared__ float sm[4];
    size_t base = (size_t)blockIdx.x * CE;
    int e = threadIdx.x * 2;
    ushort2 s = *(const ushort2*)&src[base + e];
    ushort2 a = *(const ushort2*)&ao[base + e];
    float x0 = bf2f(s.x) + bf2f(a.x), x1 = bf2f(s.y) + bf2f(a.y);
    float mu = blockSum256(x0 + x1, sm) * (1.f / CE);
    float d0 = x0 - mu, d1 = x1 - mu;
    float var = blockSum256(d0 * d0 + d1 * d1, sm) * (1.f / CE);
    float rs = rsqrtf(var + EPS);
    ushort2 w;
    w.x = f2bf(d0 * rs * g[e] + be[e]);
    w.y = f2bf(d1 * rs * g[e + 1] + be[e + 1]);
    *(ushort2*)&o[base + e] = w;
}

__global__ __launch_bounds__(256) void ln2_kernel(
    const bf16_t* __restrict__ a, const float* __restrict__ b,
    const float* __restrict__ g, const float* __restrict__ be,
    float* __restrict__ o) {
    __shared__ float sm[4];
    size_t base = (size_t)blockIdx.x * CE;
    int e = threadIdx.x * 2;
    ushort2 aa = *(const ushort2*)&a[base + e];
    float2 bb = *(const float2*)&b[base + e];
    float x0 = bf2f(aa.x) + bb.x, x1 = bf2f(aa.y) + bb.y;
    float mu = blockSum256(x0 + x1, sm) * (1.f / CE);
    float d0 = x0 - mu, d1 = x1 - mu;
    float var = blockSum256(d0 * d0 + d1 * d1, sm) * (1.f / CE);
    float rs = rsqrtf(var + EPS);
    float2 w;
    w.x = d0 * rs * g[e] + be[e];
    w.y = d1 * rs * g[e + 1] + be[e + 1];
    *(float2*)&o[base + e] = w;
}

// ---------------- host ----------------
extern "C" void kernel_launch(void* const* d_in, const int* in_sizes, int n_in,
                              void* d_out, int out_size, void* d_ws, size_t ws_size,
                              hipStream_t stream) {
    const float* src  = (const float*)d_in[0];
    const float* mask = (const float*)d_in[1];
    const float* W1   = (const float*)d_in[2];
    const float* b1   = (const float*)d_in[3];
    const float* W2   = (const float*)d_in[4];
    const float* b2   = (const float*)d_in[5];
    const float* g1   = (const float*)d_in[6];
    const float* be1  = (const float*)d_in[7];
    const float* g2   = (const float*)d_in[8];
    const float* be2  = (const float*)d_in[9];
    float* out = (float*)d_out;
    char* ws = (char*)d_ws;

    hipFuncSetAttribute(reinterpret_cast<const void*>(&gemm256<0>), hipFuncAttributeMaxDynamicSharedMemorySize, 131072);
    hipFuncSetAttribute(reinterpret_cast<const void*>(&gemm256<1>), hipFuncAttributeMaxDynamicSharedMemorySize, 131072);
    hipFuncSetAttribute(reinterpret_cast<const void*>(&gemm256<2>), hipFuncAttributeMaxDynamicSharedMemorySize, 131072);
    hipFuncSetAttribute(reinterpret_cast<const void*>(&gemm256<3>), hipFuncAttributeMaxDynamicSharedMemorySize, 131072);

    // ---- workspace layout (MiB offsets) ----
    // [0,256)   scores/probs bf16 (all 32)  | after PV: [0,64)=src2, [64,128)=ff
    // [256,320) src_bf                      | FFN: H[0:64MB)
    // [320,384) srcT                        | FFN: H[64:128MB)
    // [384,448) attnO (bf16, all 32; only 64 MB used)
    // [448,452) W1T, W2T
    const size_t MB = 1024 * 1024;
    bf16_t* probs  = (bf16_t*)(ws);              // scores in-place -> probs
    bf16_t* src_bf = (bf16_t*)(ws + 256 * MB);
    bf16_t* srcT   = (bf16_t*)(ws + 320 * MB);
    bf16_t* attnO  = (bf16_t*)(ws + 384 * MB);
    bf16_t* W1T    = (bf16_t*)(ws + 448 * MB);
    bf16_t* W2T    = (bf16_t*)(ws + 450 * MB);
    bf16_t* src2   = (bf16_t*)(ws);              // overlays probs (dead after PV)
    float*  ff     = (float*)(ws + 64 * MB);     // overlays probs[64:128MB)
    bf16_t* H      = (bf16_t*)(ws + 256 * MB);   // overlays src_bf+srcT
    if (ws_size < 452 * MB) return;

    // ---- conversions ----
    cvt_f32_bf16_vec<<<4096, 256, 0, stream>>>(src, src_bf, TOT);
    transpose_f32_bf16<<<dim3(CF / 32, CE / 32, 1), 256, 0, stream>>>(W1, W1T, CE, CF);
    transpose_f32_bf16<<<dim3(CE / 32, CF / 32, 1), 256, 0, stream>>>(W2, W2T, CF, CE);
    transpose_bf16<<<dim3(CE / 32, CN / 32, 32), 256, 0, stream>>>(
        src_bf, srcT, CN, CE, (long long)CN * CE, (long long)CE * CN);

    // ---- attention: scores (all 32, bf16, scale folded) -> softmax -> PV ----
    gemm256<3><<<dim3(CN / 256, CN / 256, 32), 512, 131072, stream>>>(
        src_bf, src_bf, probs, nullptr, SCALE, CN, CN, CE,
        (long long)CN * CE, (long long)CN * CE, (long long)CN * CN);
    softmax_bf16<<<dim3(CB * CC * CN), 256, 0, stream>>>(probs, mask);
    gemm256<3><<<dim3(CE / 256, CN / 256, 32), 512, 131072, stream>>>(
        probs, srcT, attnO, nullptr, 1.0f, CN, CE, CN,
        (long long)CN * CN, (long long)CE * CN, (long long)CN * CE);
    ln1_kernel<<<dim3(CB * CC * CN), 256, 0, stream>>>(src_bf, attnO, g1, be1, src2);

    // ---- FFN + final LN, 2 chunks ----
    for (int c = 0; c < 2; ++c) {
        const bf16_t* A2 = src2 + (size_t)c * MCH * CE;
        gemm256<1><<<dim3(CF / 256, MCH / 256, 1), 512, 131072, stream>>>(
            A2, W1T, H, b1, 1.0f, MCH, CF, CE, 0, 0, 0);
        gemm256<2><<<dim3(CE / 256, MCH / 256, 1), 512, 131072, stream>>>(
            H, W2T, ff, b2, 1.0f, MCH, CE, CF, 0, 0, 0);
        ln2_kernel<<<dim3(MCH), 256, 0, stream>>>(
            A2, ff, g2, be2, out + (size_t)c * MCH * CE);
    }
}

// Round 4
// 891.495 us; speedup vs baseline: 2.0598x; 1.0150x over previous
//
#include <hip/hip_runtime.h>
#include <stdint.h>

// ---------------- problem constants ----------------
constexpr int CB = 8, CC = 4, CN = 2048, CE = 512, CF = 2048;
constexpr long long TOT = (long long)CB * CC * CN * CE;
constexpr int GRP = 16;       // attention batches per LLC-resident group
constexpr int MCH = 65536;    // FFN rows (single chunk)
constexpr float SCALE = 0.04419417382415922f;  // 1/sqrt(512)
constexpr float MASK_SCALE = 5.0f;
constexpr float EPS = 1e-5f;

typedef unsigned short bf16_t;
typedef __attribute__((ext_vector_type(4))) float f32x4;
typedef __attribute__((ext_vector_type(8))) short s16x8;

#define DEV static __device__ __forceinline__

DEV unsigned short f2bf(float f) {
    unsigned u = __float_as_uint(f);
    unsigned r = (u + 0x7fffu + ((u >> 16) & 1u)) >> 16;
    return (unsigned short)r;
}
DEV float bf2f(unsigned short b) {
    return __uint_as_float(((unsigned)b) << 16);
}

typedef const __attribute__((address_space(1))) unsigned int* gptr_t;
typedef __attribute__((address_space(3))) unsigned int* lptr_t;
DEV void async16(const void* g, void* l) {
    __builtin_amdgcn_global_load_lds((gptr_t)g, (lptr_t)l, 16, 0, 0);
}

#define FULL_BAR() do { asm volatile("" ::: "memory"); __builtin_amdgcn_s_barrier(); asm volatile("" ::: "memory"); } while (0)
#define LGKM0() asm volatile("s_waitcnt lgkmcnt(0)" ::: "memory")

// ---------------- reductions (256-thread blocks = 4 waves) ----------------
DEV float blockSum256(float v, float* sm) {
    #pragma unroll
    for (int o = 32; o; o >>= 1) v += __shfl_xor(v, o);
    int w = threadIdx.x >> 6;
    __syncthreads();
    if ((threadIdx.x & 63) == 0) sm[w] = v;
    __syncthreads();
    return sm[0] + sm[1] + sm[2] + sm[3];
}
DEV float blockMax256(float v, float* sm) {
    #pragma unroll
    for (int o = 32; o; o >>= 1) v = fmaxf(v, __shfl_xor(v, o));
    int w = threadIdx.x >> 6;
    __syncthreads();
    if ((threadIdx.x & 63) == 0) sm[w] = v;
    __syncthreads();
    return fmaxf(fmaxf(sm[0], sm[1]), fmaxf(sm[2], sm[3]));
}

// ---------------- fp32 -> bf16 convert ----------------
__global__ __launch_bounds__(256) void cvt_f32_bf16_vec(
    const float* __restrict__ in, bf16_t* __restrict__ out, long long n) {
    long long i = ((long long)blockIdx.x * 256 + threadIdx.x) * 4;
    long long stride = (long long)gridDim.x * 1024;
    for (; i < n; i += stride) {
        float4 v = *reinterpret_cast<const float4*>(in + i);
        ushort4 u;
        u.x = f2bf(v.x); u.y = f2bf(v.y); u.z = f2bf(v.z); u.w = f2bf(v.w);
        *reinterpret_cast<ushort4*>(out + i) = u;
    }
}

// ---------------- transpose fp32[R][C] -> bf16[C][R] (weights) ----------------
__global__ __launch_bounds__(256) void transpose_f32_bf16(
    const float* __restrict__ in, bf16_t* __restrict__ out,
    int R, int Cc) {
    __shared__ float tile[32][33];
    int rb = blockIdx.y * 32, cb = blockIdx.x * 32;
    int tx = threadIdx.x & 31, ty = threadIdx.x >> 5;
    #pragma unroll
    for (int i = 0; i < 32; i += 8)
        tile[ty + i][tx] = in[(size_t)(rb + ty + i) * Cc + cb + tx];
    __syncthreads();
    #pragma unroll
    for (int i = 0; i < 32; i += 8)
        out[(size_t)(cb + ty + i) * R + rb + tx] = f2bf(tile[tx][ty + i]);
}

// ---------------- transpose bf16[R][C] -> bf16[C][R], batched via z ----------------
__global__ __launch_bounds__(256) void transpose_bf16(
    const bf16_t* __restrict__ in, bf16_t* __restrict__ out,
    int R, int Cc, long long sIn, long long sOut) {
    __shared__ bf16_t tile[32][36];
    const bf16_t* inz = in + (size_t)blockIdx.z * sIn;
    bf16_t* outz = out + (size_t)blockIdx.z * sOut;
    int rb = blockIdx.y * 32, cb = blockIdx.x * 32;
    int t = threadIdx.x;
    int r = t >> 3, c4 = (t & 7) * 4;
    *(ushort4*)&tile[r][c4] = *(const ushort4*)&inz[(size_t)(rb + r) * Cc + cb + c4];
    __syncthreads();
    int c = t >> 3, r4 = (t & 7) * 4;
    ushort4 w;
    w.x = tile[r4 + 0][c]; w.y = tile[r4 + 1][c];
    w.z = tile[r4 + 2][c]; w.w = tile[r4 + 3][c];
    *(ushort4*)&outz[(size_t)(cb + c) * R + rb + r4] = w;
}

// ============ 256x256 GEMM: C[M,Nc] = A[M,K] @ B[Nc,K]^T ============
// bf16 in, fp32 acc. 8 waves (2Mx4N), BK=64, 128KiB dyn LDS double-buffered.
// 2 phases / K-tile, ONE barrier per phase (race-freedom: every LDS read of a
// buffer is covered by an lgkmcnt(0) preceding the next barrier; all writes to
// that buffer-half occur >=1 barrier later). Counted vmcnt, never 0 mid-loop.
// XOR swizzle on 16B k-slots; XCD-aware bijective block swizzle (nwg%8==0).
// EPI 0: fp32. 1: +bias relu bf16. 2: +bias fp32. 3: alpha*bf16. 4: +bias bf16.
template <int EPI>
__global__ __launch_bounds__(512, 2) void gemm256(
    const bf16_t* __restrict__ A, const bf16_t* __restrict__ B,
    void* __restrict__ Cptr, const float* __restrict__ bias, float alpha,
    int M, int Nc, int K, long long sA, long long sB, long long sC) {
    extern __shared__ bf16_t lds[];
    bf16_t* AsL = lds;           // [dbuf2][half2][128*64]
    bf16_t* BsL = lds + 32768;

    // ---- XCD-aware bijective swizzle (requires nwg % 8 == 0) ----
    int bx, by, bz;
    {
        int gx = gridDim.x, gy = gridDim.y;
        int nwg = gx * gy * gridDim.z;
        int flat = blockIdx.x + gx * (blockIdx.y + gy * blockIdx.z);
        int wg = (nwg & 7) ? flat : ((flat & 7) * (nwg >> 3) + (flat >> 3));
        bx = wg % gx;
        int tmp = wg / gx;
        by = tmp % gy;
        bz = tmp / gy;
    }

    const bf16_t* Az = A + (size_t)bz * sA;
    const bf16_t* Bz = B + (size_t)bz * sB;
    const int t = threadIdx.x;
    const int lane = t & 63, wid = t >> 6;
    const int wr = wid >> 2, wc = wid & 3;
    const int brow = by * 256, bcol = bx * 256;
    const int NT = K >> 6;

    const int r0 = t >> 3, s0 = t & 7;
    const int ce = ((s0 ^ (r0 & 7)) << 3);      // pre-swizzled source col (elems)
    const bf16_t* aP0 = Az + (size_t)(brow + r0) * K + ce;
    const bf16_t* bP0 = Bz + (size_t)(bcol + r0) * K + ce;
    const size_t rK64 = (size_t)64 * K;
    const size_t h128K = (size_t)128 * K;

    #define STAGE_A(kt_, h_) do { \
        bf16_t* d_ = AsL + ((((kt_) & 1) * 2 + (h_)) * 8192); \
        const bf16_t* s_ = aP0 + (size_t)(h_) * h128K + (size_t)(kt_) * 64; \
        async16(s_, d_ + t * 8); \
        async16(s_ + rK64, d_ + 4096 + t * 8); \
    } while (0)
    #define STAGE_B(kt_, h_) do { \
        bf16_t* d_ = BsL + ((((kt_) & 1) * 2 + (h_)) * 8192); \
        const bf16_t* s_ = bP0 + (size_t)(h_) * h128K + (size_t)(kt_) * 64; \
        async16(s_, d_ + t * 8); \
        async16(s_ + 4096 + t * 8, d_ + 4096 + t * 8); \
    } while (0)
    // NOTE: STAGE_B second line must read s_ + rK64 (rows 64..127); fixed below.
    #undef STAGE_B
    #define STAGE_B(kt_, h_) do { \
        bf16_t* d_ = BsL + ((((kt_) & 1) * 2 + (h_)) * 8192); \
        const bf16_t* s_ = bP0 + (size_t)(h_) * h128K + (size_t)(kt_) * 64; \
        async16(s_, d_ + t * 8); \
        async16(s_ + rK64, d_ + 4096 + t * 8); \
    } while (0)

    const int q = lane >> 4, rr0 = lane & 15, xmask = rr0 & 7;
    s16x8 af[4][2];
    s16x8 bv[2][2][2];
    f32x4 acc[2][2][4][2] = {};

    #define READ_A(ktp_, qm_) do { \
        const bf16_t* base_ = AsL + (((ktp_) * 2 + (qm_)) * 8192); \
        _Pragma("unroll") for (int m_ = 0; m_ < 4; ++m_) \
        _Pragma("unroll") for (int ks_ = 0; ks_ < 2; ++ks_) \
            af[m_][ks_] = *(const s16x8*)(base_ + (wr * 64 + m_ * 16 + rr0) * 64 + (((ks_ * 4 + q) ^ xmask) << 3)); \
    } while (0)
    #define READ_B(ktp_, qn_) do { \
        const bf16_t* base_ = BsL + (((ktp_) * 2 + (qn_)) * 8192); \
        _Pragma("unroll") for (int n_ = 0; n_ < 2; ++n_) \
        _Pragma("unroll") for (int ks_ = 0; ks_ < 2; ++ks_) \
            bv[qn_][n_][ks_] = *(const s16x8*)(base_ + (wc * 32 + n_ * 16 + rr0) * 64 + (((ks_ * 4 + q) ^ xmask) << 3)); \
    } while (0)
    #define MFMA_Q(qm_, qn_) do { \
        __builtin_amdgcn_s_setprio(1); \
        _Pragma("unroll") for (int m_ = 0; m_ < 4; ++m_) \
        _Pragma("unroll") for (int n_ = 0; n_ < 2; ++n_) \
        _Pragma("unroll") for (int ks_ = 0; ks_ < 2; ++ks_) \
            acc[qm_][qn_][m_][n_] = __builtin_amdgcn_mfma_f32_16x16x32_bf16( \
                af[m_][ks_], bv[qn_][n_][ks_], acc[qm_][qn_][m_][n_], 0, 0, 0); \
        __builtin_amdgcn_s_setprio(0); \
    } while (0)

    // ---- prologue: stage tile 0; A(0,1) may stay in flight ----
    STAGE_A(0, 0); STAGE_B(0, 0); STAGE_B(0, 1); STAGE_A(0, 1);
    asm volatile("s_waitcnt vmcnt(2)" ::: "memory");
    FULL_BAR();

    for (int kt = 0; kt < NT; ++kt) {
        const int ktp = kt & 1;
        // ---- phase 0: quadrants (0,0),(0,1) ----
        READ_A(ktp, 0);
        READ_B(ktp, 0);
        READ_B(ktp, 1);
        if (kt + 1 < NT) {
            STAGE_A(kt + 1, 0); STAGE_B(kt + 1, 0); STAGE_B(kt + 1, 1);
            asm volatile("s_waitcnt vmcnt(6)" ::: "memory");   // drains A(kt,1)
        } else {
            asm volatile("s_waitcnt vmcnt(0)" ::: "memory");
        }
        FULL_BAR();
        LGKM0();
        MFMA_Q(0, 0);
        MFMA_Q(0, 1);
        // ---- phase 1: quadrants (1,0),(1,1) ----
        READ_A(ktp, 1);
        if (kt + 1 < NT) {
            STAGE_A(kt + 1, 1);
            asm volatile("s_waitcnt vmcnt(2)" ::: "memory");   // drains A/B(kt+1,0),B(kt+1,1)
        }
        FULL_BAR();
        LGKM0();
        MFMA_Q(1, 0);
        MFMA_Q(1, 1);
    }

    // ---- epilogue ----
    size_t cz = (size_t)bz * sC;
    #pragma unroll
    for (int qm = 0; qm < 2; ++qm)
    #pragma unroll
    for (int qn = 0; qn < 2; ++qn)
    #pragma unroll
    for (int m = 0; m < 4; ++m)
    #pragma unroll
    for (int n = 0; n < 2; ++n) {
        int col = bcol + qn * 128 + wc * 32 + n * 16 + (lane & 15);
        float bvv = (EPI == 1 || EPI == 2 || EPI == 4) ? bias[col] : 0.f;
        #pragma unroll
        for (int j = 0; j < 4; ++j) {
            int row = brow + qm * 128 + wr * 64 + m * 16 + q * 4 + j;
            float v = acc[qm][qn][m][n][j] + bvv;
            if constexpr (EPI == 1)
                ((bf16_t*)Cptr)[cz + (size_t)row * Nc + col] = f2bf(fmaxf(v, 0.f));
            else if constexpr (EPI == 3)
                ((bf16_t*)Cptr)[cz + (size_t)row * Nc + col] = f2bf(v * alpha);
            else if constexpr (EPI == 4)
                ((bf16_t*)Cptr)[cz + (size_t)row * Nc + col] = f2bf(v);
            else
                ((float*)Cptr)[cz + (size_t)row * Nc + col] = v;
        }
    }
    #undef STAGE_A
    #undef STAGE_B
    #undef READ_A
    #undef READ_B
    #undef MFMA_Q
}

// ---------------- softmax: bf16 scores (pre-scaled) in-place -> bf16 probs ---
__global__ __launch_bounds__(256) void softmax_bf16(
    bf16_t* __restrict__ S, const float* __restrict__ mask, int bc0) {
    __shared__ float sm[4];
    int gr = blockIdx.x;
    int b = (bc0 + (gr >> 11)) >> 2;
    bf16_t* row = S + (size_t)gr * CN;
    int tid = threadIdx.x;
    const float* mrow = mask + (size_t)b * CN + tid * 8;
    s16x8 v = *(const s16x8*)(row + tid * 8);
    float4 m0 = *(const float4*)(mrow);
    float4 m1 = *(const float4*)(mrow + 4);
    float x[8];
    x[0] = bf2f((unsigned short)v[0]) - m0.x * MASK_SCALE;
    x[1] = bf2f((unsigned short)v[1]) - m0.y * MASK_SCALE;
    x[2] = bf2f((unsigned short)v[2]) - m0.z * MASK_SCALE;
    x[3] = bf2f((unsigned short)v[3]) - m0.w * MASK_SCALE;
    x[4] = bf2f((unsigned short)v[4]) - m1.x * MASK_SCALE;
    x[5] = bf2f((unsigned short)v[5]) - m1.y * MASK_SCALE;
    x[6] = bf2f((unsigned short)v[6]) - m1.z * MASK_SCALE;
    x[7] = bf2f((unsigned short)v[7]) - m1.w * MASK_SCALE;
    float mx = -3.4e38f;
    #pragma unroll
    for (int i = 0; i < 8; i++) mx = fmaxf(mx, x[i]);
    mx = blockMax256(mx, sm);
    float s = 0.f;
    #pragma unroll
    for (int i = 0; i < 8; i++) { x[i] = __expf(x[i] - mx); s += x[i]; }
    s = blockSum256(s, sm);
    float inv = 1.f / s;
    s16x8 u;
    #pragma unroll
    for (int i = 0; i < 8; i++) u[i] = (short)f2bf(x[i] * inv);
    *(s16x8*)(row + tid * 8) = u;
}

// ---------------- residual + layernorm kernels (E=512, one block/row) --------
__global__ __launch_bounds__(256) void ln1_kernel(
    const bf16_t* __restrict__ src, const bf16_t* __restrict__ ao,
    const float* __restrict__ g, const float* __restrict__ be,
    bf16_t* __restrict__ o) {
    __shared__ float sm[4];
    size_t base = (size_t)blockIdx.x * CE;
    int e = threadIdx.x * 2;
    ushort2 s = *(const ushort2*)&src[base + e];
    ushort2 a = *(const ushort2*)&ao[base + e];
    float x0 = bf2f(s.x) + bf2f(a.x), x1 = bf2f(s.y) + bf2f(a.y);
    float mu = blockSum256(x0 + x1, sm) * (1.f / CE);
    float d0 = x0 - mu, d1 = x1 - mu;
    float var = blockSum256(d0 * d0 + d1 * d1, sm) * (1.f / CE);
    float rs = rsqrtf(var + EPS);
    ushort2 w;
    w.x = f2bf(d0 * rs * g[e] + be[e]);
    w.y = f2bf(d1 * rs * g[e + 1] + be[e + 1]);
    *(ushort2*)&o[base + e] = w;
}

__global__ __launch_bounds__(256) void ln2_kernel(
    const bf16_t* __restrict__ a, const bf16_t* __restrict__ b,
    const float* __restrict__ g, const float* __restrict__ be,
    float* __restrict__ o) {
    __shared__ float sm[4];
    size_t base = (size_t)blockIdx.x * CE;
    int e = threadIdx.x * 2;
    ushort2 aa = *(const ushort2*)&a[base + e];
    ushort2 bb = *(const ushort2*)&b[base + e];
    float x0 = bf2f(aa.x) + bf2f(bb.x), x1 = bf2f(aa.y) + bf2f(bb.y);
    float mu = blockSum256(x0 + x1, sm) * (1.f / CE);
    float d0 = x0 - mu, d1 = x1 - mu;
    float var = blockSum256(d0 * d0 + d1 * d1, sm) * (1.f / CE);
    float rs = rsqrtf(var + EPS);
    float2 w;
    w.x = d0 * rs * g[e] + be[e];
    w.y = d1 * rs * g[e + 1] + be[e + 1];
    *(float2*)&o[base + e] = w;
}

// ---------------- host ----------------
extern "C" void kernel_launch(void* const* d_in, const int* in_sizes, int n_in,
                              void* d_out, int out_size, void* d_ws, size_t ws_size,
                              hipStream_t stream) {
    const float* src  = (const float*)d_in[0];
    const float* mask = (const float*)d_in[1];
    const float* W1   = (const float*)d_in[2];
    const float* b1   = (const float*)d_in[3];
    const float* W2   = (const float*)d_in[4];
    const float* b2   = (const float*)d_in[5];
    const float* g1   = (const float*)d_in[6];
    const float* be1  = (const float*)d_in[7];
    const float* g2   = (const float*)d_in[8];
    const float* be2  = (const float*)d_in[9];
    float* out = (float*)d_out;
    char* ws = (char*)d_ws;

    hipFuncSetAttribute(reinterpret_cast<const void*>(&gemm256<1>), hipFuncAttributeMaxDynamicSharedMemorySize, 131072);
    hipFuncSetAttribute(reinterpret_cast<const void*>(&gemm256<3>), hipFuncAttributeMaxDynamicSharedMemorySize, 131072);
    hipFuncSetAttribute(reinterpret_cast<const void*>(&gemm256<4>), hipFuncAttributeMaxDynamicSharedMemorySize, 131072);

    // ---- workspace layout (MiB offsets) ----
    // [0,256)   scores/probs bf16 (all 32)  | FFN: [0,64)=src2, [64,128)=ff, [128,384)=H
    // [256,320) src_bf
    // [320,384) srcT
    // [384,448) attnO (bf16)
    // [448,452) W1T, W2T
    const size_t MB = 1024 * 1024;
    bf16_t* probs  = (bf16_t*)(ws);              // scores in-place -> probs
    bf16_t* src_bf = (bf16_t*)(ws + 256 * MB);
    bf16_t* srcT   = (bf16_t*)(ws + 320 * MB);
    bf16_t* attnO  = (bf16_t*)(ws + 384 * MB);
    bf16_t* W1T    = (bf16_t*)(ws + 448 * MB);
    bf16_t* W2T    = (bf16_t*)(ws + 450 * MB);
    bf16_t* src2   = (bf16_t*)(ws);              // overlays probs (dead after PV)
    bf16_t* ff     = (bf16_t*)(ws + 64 * MB);    // overlays probs
    bf16_t* H      = (bf16_t*)(ws + 128 * MB);   // overlays probs tail
    if (ws_size < 452 * MB) return;

    // ---- conversions ----
    cvt_f32_bf16_vec<<<4096, 256, 0, stream>>>(src, src_bf, TOT);
    transpose_f32_bf16<<<dim3(CF / 32, CE / 32, 1), 256, 0, stream>>>(W1, W1T, CE, CF);
    transpose_f32_bf16<<<dim3(CE / 32, CF / 32, 1), 256, 0, stream>>>(W2, W2T, CF, CE);
    transpose_bf16<<<dim3(CE / 32, CN / 32, 32), 256, 0, stream>>>(
        src_bf, srcT, CN, CE, (long long)CN * CE, (long long)CE * CN);

    // ---- attention in LLC-resident groups: scores -> softmax -> PV ----
    for (int g0 = 0; g0 < CB * CC; g0 += GRP) {
        const bf16_t* srcb = src_bf + (size_t)g0 * CN * CE;
        bf16_t* probs_g = probs + (size_t)g0 * CN * CN;
        gemm256<3><<<dim3(CN / 256, CN / 256, GRP), 512, 131072, stream>>>(
            srcb, srcb, probs_g, nullptr, SCALE, CN, CN, CE,
            (long long)CN * CE, (long long)CN * CE, (long long)CN * CN);
        softmax_bf16<<<dim3(GRP * CN), 256, 0, stream>>>(probs_g, mask, g0);
        gemm256<3><<<dim3(CE / 256, CN / 256, GRP), 512, 131072, stream>>>(
            probs_g, srcT + (size_t)g0 * CE * CN, attnO + (size_t)g0 * CN * CE,
            nullptr, 1.0f, CN, CE, CN,
            (long long)CN * CN, (long long)CE * CN, (long long)CN * CE);
    }
    ln1_kernel<<<dim3(CB * CC * CN), 256, 0, stream>>>(src_bf, attnO, g1, be1, src2);

    // ---- FFN + final LN (single chunk) ----
    gemm256<1><<<dim3(CF / 256, MCH / 256, 1), 512, 131072, stream>>>(
        src2, W1T, H, b1, 1.0f, MCH, CF, CE, 0, 0, 0);
    gemm256<4><<<dim3(CE / 256, MCH / 256, 1), 512, 131072, stream>>>(
        H, W2T, ff, b2, 1.0f, MCH, CE, CF, 0, 0, 0);
    ln2_kernel<<<dim3(MCH), 256, 0, stream>>>(src2, ff, g2, be2, out);
}